// Round 13
// baseline (124.538 us; speedup 1.0000x reference)
//
#include <hip/hip_runtime.h>
#include <hip/hip_bf16.h>
#include <stdint.h>

typedef __attribute__((ext_vector_type(8))) __bf16 bf16x8;
typedef __attribute__((ext_vector_type(4))) float f32x4;
typedef unsigned short u16;

__device__ __forceinline__ u16 f2bf(float f) {
  unsigned u = __builtin_bit_cast(unsigned, f);
  unsigned r = 0x7FFFu + ((u >> 16) & 1u);
  return (u16)((u + r) >> 16);
}

__device__ __forceinline__ __bf16 f2bf_v(float f) {
  __hip_bfloat16 h = __float2bfloat16(f);
  return __builtin_bit_cast(__bf16, h);
}

__device__ __forceinline__ void gload16(const void* g, void* l) {
  __builtin_amdgcn_global_load_lds(
      (__attribute__((address_space(1))) void*)(g),
      (__attribute__((address_space(3))) void*)(l),
      16, 0, 0);
}

#define SYNC_LGKM() do { asm volatile("s_waitcnt lgkmcnt(0)" ::: "memory"); \
                         __builtin_amdgcn_s_barrier(); } while (0)
#define SYNC_VM()   do { asm volatile("s_waitcnt vmcnt(0)" ::: "memory");   \
                         __builtin_amdgcn_s_barrier(); } while (0)

// ---- deg / rsqrt -----------------------------------------------------------
__global__ void row_deg_k(const float* __restrict__ adj, float* __restrict__ dis, int N) {
  int row = blockIdx.x;
  const float4* a = (const float4*)(adj + (size_t)row * N);
  float s = 0.f;
  for (int j = threadIdx.x; j < N / 4; j += 256) {
    float4 v = a[j];
    s += v.x + v.y + v.z + v.w;
  }
#pragma unroll
  for (int off = 32; off > 0; off >>= 1) s += __shfl_down(s, off, 64);
  __shared__ float wsum[4];
  if ((threadIdx.x & 63) == 0) wsum[threadIdx.x >> 6] = s;
  __syncthreads();
  if (threadIdx.x == 0) {
    float t = wsum[0] + wsum[1] + wsum[2] + wsum[3];
    dis[row] = (t > 0.f) ? (1.0f / sqrtf(t)) : 0.f;
  }
}

// ---- W [512,512] -> W^T bf16 ----------------------------------------------
__global__ void conv_wt_k(const float* __restrict__ w, u16* __restrict__ wt) {
  int idx = blockIdx.x * 256 + threadIdx.x;  // 262144 total
  int i = idx >> 9, o = idx & 511;
  wt[o * 512 + i] = f2bf(w[idx]);
}

// ---- norm_adj bf16 ---------------------------------------------------------
__global__ void make_nadj_k(const float* __restrict__ adj, const float* __restrict__ dis,
                            u16* __restrict__ o, int N) {
  int idx = blockIdx.x * 256 + threadIdx.x;  // per float4, N*N/4 total
  int i = idx >> 9;                          // N/4 = 512 float4 per row
  int j4 = (idx & 511) * 4;
  float di = dis[i];
  float4 a = ((const float4*)adj)[idx];
  ushort4 u;
  u.x = f2bf(a.x * di * dis[j4 + 0]);
  u.y = f2bf(a.y * di * dis[j4 + 1]);
  u.z = f2bf(a.z * di * dis[j4 + 2]);
  u.w = f2bf(a.w * di * dis[j4 + 3]);
  ((ushort4*)o)[idx] = u;
}

// ============================================================================
// Shared GEMM structure: 128x256 tile, BK=64, 8 waves (2Mx4N, wave 64x64),
// 2 blocks/CU (80 KiB LDS: A[128][64] @0 single-buf, B[2][256][64] @8192 dbuf).
// Per tile t: { WRITE_A(t) from regs (swizzled ds_write) ;
//               LOADA(t+1)->regs ; STAGE_B(t+1)->bufB[cn] (DMA, pre-swz src) ;
//               lgkmcnt(0)+barrier   [publishes A writes; vmcnt NOT drained]
//               compute(t)           [16 ds_read_b128 + 32 MFMA, unpinned]
//               vmcnt(0)+barrier }   [B(t+1)/A(t+1) landed: issued 1 tile ago]
// Swizzle elem ^= (row&7)<<3 on ds_write dest / DMA global source / ds_read.
// ============================================================================

// ---- GEMM1d: Ct = (X @ Wt^T)^T, A = fp32 X reg-staged + cvt ----------------
__launch_bounds__(512, 4)
__global__ void gemm1d_k(const float* __restrict__ X,
                         const u16* __restrict__ Wt,
                         u16* __restrict__ Ct, int M) {
  __shared__ __align__(16) u16 lds[40960];  // A 8192 elem @0, B 2x16384 @8192

  const int tid = threadIdx.x;
  const int lane = tid & 63;
  const int wid = tid >> 6;
  const int wr = wid >> 2;
  const int wc = wid & 3;

  // XCD swizzle; n-pair of one m-tile adjacent (same chunk) for X L2 reuse
  const int flat = blockIdx.x;
  const int wg = (flat & 7) * 64 + (flat >> 3);   // grid 512
  const int m_t = wg >> 1;
  const int n_t = wg & 1;
  const int rowBase = m_t * 128;
  const int colBase = n_t * 256;

  // A staging: rows rA, rA+64 (rA = tid>>3), 8 elems at kk; linear global,
  // swizzled LDS dest. B staging: 4 rows via DMA; pre-swz source, linear dest.
  const int rA = tid >> 3;
  const int kk = (tid & 7) * 8;
  const int swz = (rA & 7) << 3;                  // rows rA+64k share swz
  const float* gX = X + (size_t)(rowBase + rA) * 512 + kk;
  u16* lAw = lds + rA * 64 + (kk ^ swz);
  const u16* gB = Wt + (size_t)(colBase + rA) * 512 + (kk ^ swz);
  u16* lBd = lds + 8192 + rA * 64 + kk;           // = 8192 + tid*8

  // fragment reads
  const int fr = lane & 15;
  const int rsw = (lane & 7) << 3;
  const int kp0 = ((lane >> 4) * 8) ^ rsw;
  const int kp1 = (32 | ((lane >> 4) * 8)) ^ rsw;
  const u16* fA = lds + (wr * 64 + fr) * 64;
  const u16* fB = lds + 8192 + (wc * 64 + fr) * 64;

  f32x4 acc[4][4] = {};
  f32x4 xv[2][2];  // [row 0/64][lo/hi quad]

  const int NT = 8;  // K=512, BK=64

#define LOADX(t)                                                                     \
  do {                                                                               \
    xv[0][0] = *(const f32x4*)(gX + (t) * 64);                                       \
    xv[0][1] = *(const f32x4*)(gX + (t) * 64 + 4);                                   \
    xv[1][0] = *(const f32x4*)(gX + (size_t)64 * 512 + (t) * 64);                    \
    xv[1][1] = *(const f32x4*)(gX + (size_t)64 * 512 + (t) * 64 + 4);                \
  } while (0)

#define WRITE_A()                                                                    \
  _Pragma("unroll") for (int h = 0; h < 2; ++h) {                                    \
    bf16x8 v;                                                                        \
    _Pragma("unroll") for (int i = 0; i < 4; ++i) {                                  \
      v[i] = f2bf_v(xv[h][0][i]); v[4 + i] = f2bf_v(xv[h][1][i]);                    \
    }                                                                                \
    *(bf16x8*)(lAw + h * 4096) = v;                                                  \
  }

#define STAGE_B1(d, t)                                                               \
  _Pragma("unroll") for (int r4 = 0; r4 < 4; ++r4)                                   \
    gload16(gB + (size_t)(r4 * 64) * 512 + (t) * 64, lBd + (d) * 16384 + r4 * 4096);

  // prologue: A(0)->regs, B(0)->buf0, drain, publish
  LOADX(0);
  STAGE_B1(0, 0);
  SYNC_VM();

  for (int t = 0; t < NT; ++t) {
    const int c = t & 1;
    const int cn = c ^ 1;
    const int tn = (t + 1 < NT) ? t + 1 : NT - 1;  // clamp: staged/loaded, unread

    WRITE_A();           // A(t) regs -> LDS (vmcnt already 0 from prev sync)
    LOADX(tn);           // A(t+1) -> regs
    STAGE_B1(cn, tn);    // B(t+1) -> other buffer
    SYNC_LGKM();         // publish A writes; B/X stay in flight

    bf16x8 a0[4], a1[4], b0[4], b1[4];
#pragma unroll
    for (int m = 0; m < 4; ++m) {
      a0[m] = *(const bf16x8*)(fA + m * 1024 + kp0);
      a1[m] = *(const bf16x8*)(fA + m * 1024 + kp1);
    }
#pragma unroll
    for (int n = 0; n < 4; ++n) {
      b0[n] = *(const bf16x8*)(fB + c * 16384 + n * 1024 + kp0);
      b1[n] = *(const bf16x8*)(fB + c * 16384 + n * 1024 + kp1);
    }
#pragma unroll
    for (int m = 0; m < 4; ++m)
#pragma unroll
      for (int n = 0; n < 4; ++n)
        acc[m][n] = __builtin_amdgcn_mfma_f32_16x16x32_bf16(a0[m], b0[n], acc[m][n], 0, 0, 0);
#pragma unroll
    for (int m = 0; m < 4; ++m)
#pragma unroll
      for (int n = 0; n < 4; ++n)
        acc[m][n] = __builtin_amdgcn_mfma_f32_16x16x32_bf16(a1[m], b1[n], acc[m][n], 0, 0, 0);

    SYNC_VM();           // B(t+1)/A(t+1) landed (issued a full tile ago)
  }

  // epilogue: bf16 C^T write
#pragma unroll
  for (int m = 0; m < 4; ++m) {
    const int r = rowBase + wr * 64 + m * 16 + (lane >> 4) * 4;
#pragma unroll
    for (int n = 0; n < 4; ++n) {
      const int cc = colBase + wc * 64 + n * 16 + fr;
      ushort4 v;
      v.x = f2bf(acc[m][n][0]);
      v.y = f2bf(acc[m][n][1]);
      v.z = f2bf(acc[m][n][2]);
      v.w = f2bf(acc[m][n][3]);
      *reinterpret_cast<ushort4*>(&Ct[(size_t)cc * M + r]) = v;
    }
  }
#undef LOADX
#undef WRITE_A
#undef STAGE_B1
}

// ---- GEMM2d: C = A[M,K]*Bt[N,K]^T + bias, A = bf16 reg-staged --------------
__launch_bounds__(512, 4)
__global__ void gemm2d_k(const u16* __restrict__ A, int lda,
                         const u16* __restrict__ Bt, int ldb,
                         float* __restrict__ C, int ldc,
                         const float* __restrict__ bias, int K,
                         int nMT, int nNT, size_t zBt, size_t zC) {
  __shared__ __align__(16) u16 lds[40960];  // A 8192 @0, B 2x16384 @8192

  const int tid = threadIdx.x;
  const int lane = tid & 63;
  const int wid = tid >> 6;
  const int wr = wid >> 2;
  const int wc = wid & 3;

  const int flat = blockIdx.x;
  const int cpx = (int)gridDim.x >> 3;
  const int wg = (flat & 7) * cpx + (flat >> 3);
  const int m_t = wg % nMT;
  const int rest = wg / nMT;
  const int n_t = rest % nNT;
  const int b = rest / nNT;
  const int rowBase = m_t * 128;
  const int colBase = n_t * 256;
  const u16* Bb = Bt + (size_t)b * zBt;

  const int rA = tid >> 3;
  const int kk = (tid & 7) * 8;
  const int swz = (rA & 7) << 3;
  const u16* gA = A + (size_t)(rowBase + rA) * lda + kk;      // linear (reg path)
  u16* lAw = lds + rA * 64 + (kk ^ swz);
  const u16* gB = Bb + (size_t)(colBase + rA) * ldb + (kk ^ swz);  // pre-swz (DMA)
  u16* lBd = lds + 8192 + rA * 64 + kk;

  const int fr = lane & 15;
  const int rsw = (lane & 7) << 3;
  const int kp0 = ((lane >> 4) * 8) ^ rsw;
  const int kp1 = (32 | ((lane >> 4) * 8)) ^ rsw;
  const u16* fA = lds + (wr * 64 + fr) * 64;
  const u16* fB = lds + 8192 + (wc * 64 + fr) * 64;

  f32x4 acc[4][4] = {};
  bf16x8 aR[2];

  const int NT = K >> 6;

#define LOADA(t)                                                                     \
  do {                                                                               \
    aR[0] = *(const bf16x8*)(gA + (t) * 64);                                         \
    aR[1] = *(const bf16x8*)(gA + (size_t)64 * lda + (t) * 64);                      \
  } while (0)

#define WRITE_A()                                                                    \
  do { *(bf16x8*)(lAw) = aR[0]; *(bf16x8*)(lAw + 4096) = aR[1]; } while (0)

#define STAGE_B1(d, t)                                                               \
  _Pragma("unroll") for (int r4 = 0; r4 < 4; ++r4)                                   \
    gload16(gB + (size_t)(r4 * 64) * ldb + (t) * 64, lBd + (d) * 16384 + r4 * 4096);

  LOADA(0);
  STAGE_B1(0, 0);
  SYNC_VM();

  for (int t = 0; t < NT; ++t) {
    const int c = t & 1;
    const int cn = c ^ 1;
    const int tn = (t + 1 < NT) ? t + 1 : NT - 1;

    WRITE_A();
    LOADA(tn);
    STAGE_B1(cn, tn);
    SYNC_LGKM();

    bf16x8 a0[4], a1[4], b0[4], b1[4];
#pragma unroll
    for (int m = 0; m < 4; ++m) {
      a0[m] = *(const bf16x8*)(fA + m * 1024 + kp0);
      a1[m] = *(const bf16x8*)(fA + m * 1024 + kp1);
    }
#pragma unroll
    for (int n = 0; n < 4; ++n) {
      b0[n] = *(const bf16x8*)(fB + c * 16384 + n * 1024 + kp0);
      b1[n] = *(const bf16x8*)(fB + c * 16384 + n * 1024 + kp1);
    }
#pragma unroll
    for (int m = 0; m < 4; ++m)
#pragma unroll
      for (int n = 0; n < 4; ++n)
        acc[m][n] = __builtin_amdgcn_mfma_f32_16x16x32_bf16(a0[m], b0[n], acc[m][n], 0, 0, 0);
#pragma unroll
    for (int m = 0; m < 4; ++m)
#pragma unroll
      for (int n = 0; n < 4; ++n)
        acc[m][n] = __builtin_amdgcn_mfma_f32_16x16x32_bf16(a1[m], b1[n], acc[m][n], 0, 0, 0);

    SYNC_VM();
  }

  float* Cb = C + (size_t)b * zC;
#pragma unroll
  for (int n = 0; n < 4; ++n) {
    const int cc = colBase + wc * 64 + n * 16 + fr;
    const float bv = bias[cc];
#pragma unroll
    for (int m = 0; m < 4; ++m) {
      const int r = rowBase + wr * 64 + m * 16 + (lane >> 4) * 4;
#pragma unroll
      for (int j = 0; j < 4; ++j)
        Cb[(size_t)(r + j) * ldc + cc] = acc[m][n][j] + bv;
    }
  }
#undef LOADA
#undef WRITE_A
#undef STAGE_B1
}

extern "C" void kernel_launch(void* const* d_in, const int* in_sizes, int n_in,
                              void* d_out, int out_size, void* d_ws, size_t ws_size,
                              hipStream_t stream) {
  const int B = 16, N = 2048, FIN = 512, FOUT = 512;
  const float* x    = (const float*)d_in[0];
  const float* adj  = (const float*)d_in[1];
  const float* w    = (const float*)d_in[2];
  const float* bias = (const float*)d_in[3];
  float* out = (float*)d_out;
  char* ws = (char*)d_ws;

  float* dis = (float*)ws;                       // 8 KB
  u16* wt    = (u16*)(ws + 8192);                // 512 KB  W^T [FOUT][FIN]
  u16* nadj  = (u16*)(ws + 532480);              // 8 MB    [N][N]
  u16* st    = (u16*)(ws + 8921088);             // 32 MB   support^T [FOUT][B*N]

  row_deg_k<<<N, 256, 0, stream>>>(adj, dis, N);
  conv_wt_k<<<(FIN * FOUT) / 256, 256, 0, stream>>>(w, wt);
  make_nadj_k<<<(N * N / 4) / 256, 256, 0, stream>>>(adj, dis, nadj, N);

  // GEMM1d: st = (x @ wt^T)^T ; grid 256m*2n = 512 blocks (2/CU)
  gemm1d_k<<<dim3(512), 512, 0, stream>>>(x, wt, st, B * N);

  // GEMM2d: out[b] = nadj @ support[b] + bias ; grid 16*2*16 = 512 (2/CU)
  gemm2d_k<<<dim3(512), 512, 0, stream>>>(
      nadj, N, st, B * N, out, FOUT, bias, N, 16, 2,
      (size_t)N, (size_t)N * FOUT);
}

// Round 14
// 114.694 us; speedup vs baseline: 1.0858x; 1.0858x over previous
//
#include <hip/hip_runtime.h>
#include <hip/hip_bf16.h>
#include <stdint.h>

typedef __attribute__((ext_vector_type(8))) __bf16 bf16x8;
typedef __attribute__((ext_vector_type(4))) float f32x4;
typedef unsigned short u16;

__device__ __forceinline__ u16 f2bf(float f) {
  unsigned u = __builtin_bit_cast(unsigned, f);
  unsigned r = 0x7FFFu + ((u >> 16) & 1u);
  return (u16)((u + r) >> 16);
}

__device__ __forceinline__ __bf16 f2bf_v(float f) {
  __hip_bfloat16 h = __float2bfloat16(f);
  return __builtin_bit_cast(__bf16, h);
}

__device__ __forceinline__ void gload16(const void* g, void* l) {
  __builtin_amdgcn_global_load_lds(
      (__attribute__((address_space(1))) void*)(g),
      (__attribute__((address_space(3))) void*)(l),
      16, 0, 0);
}

// ---- deg / rsqrt -----------------------------------------------------------
__global__ void row_deg_k(const float* __restrict__ adj, float* __restrict__ dis, int N) {
  int row = blockIdx.x;
  const float4* a = (const float4*)(adj + (size_t)row * N);
  float s = 0.f;
  for (int j = threadIdx.x; j < N / 4; j += 256) {
    float4 v = a[j];
    s += v.x + v.y + v.z + v.w;
  }
#pragma unroll
  for (int off = 32; off > 0; off >>= 1) s += __shfl_down(s, off, 64);
  __shared__ float wsum[4];
  if ((threadIdx.x & 63) == 0) wsum[threadIdx.x >> 6] = s;
  __syncthreads();
  if (threadIdx.x == 0) {
    float t = wsum[0] + wsum[1] + wsum[2] + wsum[3];
    dis[row] = (t > 0.f) ? (1.0f / sqrtf(t)) : 0.f;
  }
}

// ---- W [512,512] -> W^T bf16 ----------------------------------------------
__global__ void conv_wt_k(const float* __restrict__ w, u16* __restrict__ wt) {
  int idx = blockIdx.x * 256 + threadIdx.x;  // 262144 total
  int i = idx >> 9, o = idx & 511;
  wt[o * 512 + i] = f2bf(w[idx]);
}

// ---- norm_adj bf16 ---------------------------------------------------------
__global__ void make_nadj_k(const float* __restrict__ adj, const float* __restrict__ dis,
                            u16* __restrict__ o, int N) {
  int idx = blockIdx.x * 256 + threadIdx.x;  // per float4, N*N/4 total
  int i = idx >> 9;                          // N/4 = 512 float4 per row
  int j4 = (idx & 511) * 4;
  float di = dis[i];
  float4 a = ((const float4*)adj)[idx];
  ushort4 u;
  u.x = f2bf(a.x * di * dis[j4 + 0]);
  u.y = f2bf(a.y * di * dis[j4 + 1]);
  u.z = f2bf(a.z * di * dis[j4 + 2]);
  u.w = f2bf(a.w * di * dis[j4 + 3]);
  ((ushort4*)o)[idx] = u;
}

// ---- GEMM1e: Ct = (X @ Wt^T)^T -- gemm2b structure, A = fp32 X + cvt -------
// 128x256 tile, BK=64, single-buffered 48 KiB LDS (A[128][64] @0,
// B[256][64] @8192 elem), 8 waves (2Mx4N, wave 64x64), 2 blocks/CU.
// Per tile: {STAGE_B(t) DMA + WRITE_A(t) from regs -> sync -> LOADX(t+1)
// -> compute (16 ds_read + 32 MFMA) -> sync}. Swizzle elem ^= (row&7)<<3.
__launch_bounds__(512, 4)
__global__ void gemm1e_k(const float* __restrict__ X,
                         const u16* __restrict__ Wt,
                         u16* __restrict__ Ct, int M) {
  __shared__ __align__(16) u16 lds[24576];  // 48 KiB

  const int tid = threadIdx.x;
  const int lane = tid & 63;
  const int wid = tid >> 6;
  const int wr = wid >> 2;
  const int wc = wid & 3;

  // XCD swizzle; n-pair of one m-tile adjacent (same chunk) for X L2 reuse
  const int flat = blockIdx.x;
  const int wg = (flat & 7) * 64 + (flat >> 3);   // grid 512
  const int m_t = wg >> 1;
  const int n_t = wg & 1;
  const int rowBase = m_t * 128;
  const int colBase = n_t * 256;

  // A: fp32 reg-stage, rows rA, rA+64; swizzled ds_write dest.
  // B: DMA, 4 rows rA+64*r4; pre-swizzled source, linear dest.
  const int rA = tid >> 3;
  const int kk = (tid & 7) * 8;
  const int swz = (rA & 7) << 3;
  const float* gX = X + (size_t)(rowBase + rA) * 512 + kk;
  u16* lAw = lds + rA * 64 + (kk ^ swz);
  const u16* gB = Wt + (size_t)(colBase + rA) * 512 + (kk ^ swz);
  u16* lBd = lds + 8192 + rA * 64 + kk;

  // fragment reads
  const int fr = lane & 15;
  const int rsw = (lane & 7) << 3;
  const int kp0 = ((lane >> 4) * 8) ^ rsw;
  const int kp1 = (32 | ((lane >> 4) * 8)) ^ rsw;
  const u16* fA = lds + (wr * 64 + fr) * 64;
  const u16* fB = lds + 8192 + (wc * 64 + fr) * 64;

  f32x4 acc[4][4] = {};
  f32x4 xv[2][2];  // [row 0/64][lo/hi quad]

  const int NT = 8;  // K=512, BK=64

#define LOADX(t)                                                                     \
  do {                                                                               \
    xv[0][0] = *(const f32x4*)(gX + (t) * 64);                                       \
    xv[0][1] = *(const f32x4*)(gX + (t) * 64 + 4);                                   \
    xv[1][0] = *(const f32x4*)(gX + (size_t)64 * 512 + (t) * 64);                    \
    xv[1][1] = *(const f32x4*)(gX + (size_t)64 * 512 + (t) * 64 + 4);                \
  } while (0)

#define WRITE_A()                                                                    \
  _Pragma("unroll") for (int h = 0; h < 2; ++h) {                                    \
    bf16x8 v;                                                                        \
    _Pragma("unroll") for (int i = 0; i < 4; ++i) {                                  \
      v[i] = f2bf_v(xv[h][0][i]); v[4 + i] = f2bf_v(xv[h][1][i]);                    \
    }                                                                                \
    *(bf16x8*)(lAw + h * 4096) = v;                                                  \
  }

#define STAGE_B1(t)                                                                  \
  _Pragma("unroll") for (int r4 = 0; r4 < 4; ++r4)                                   \
    gload16(gB + (size_t)(r4 * 64) * 512 + (t) * 64, lBd + r4 * 4096);

  // prologue: X(0) -> regs
  LOADX(0);

  for (int t = 0; t < NT; ++t) {
    const int tn = (t + 1 < NT) ? t + 1 : NT - 1;  // clamp: loaded, never written

    STAGE_B1(t);         // B(t) DMA -> LDS
    WRITE_A();           // A(t) regs -> LDS (consumes xv)
    __syncthreads();     // publish tile t (drains DMA vm + ds_write lgkm)

    LOADX(tn);           // X(t+1) -> regs; latency hides under compute

    bf16x8 a0[4], a1[4], b0[4], b1[4];
#pragma unroll
    for (int m = 0; m < 4; ++m) {
      a0[m] = *(const bf16x8*)(fA + m * 1024 + kp0);
      a1[m] = *(const bf16x8*)(fA + m * 1024 + kp1);
    }
#pragma unroll
    for (int n = 0; n < 4; ++n) {
      b0[n] = *(const bf16x8*)(fB + n * 1024 + kp0);
      b1[n] = *(const bf16x8*)(fB + n * 1024 + kp1);
    }
#pragma unroll
    for (int m = 0; m < 4; ++m)
#pragma unroll
      for (int n = 0; n < 4; ++n)
        acc[m][n] = __builtin_amdgcn_mfma_f32_16x16x32_bf16(a0[m], b0[n], acc[m][n], 0, 0, 0);
#pragma unroll
    for (int m = 0; m < 4; ++m)
#pragma unroll
      for (int n = 0; n < 4; ++n)
        acc[m][n] = __builtin_amdgcn_mfma_f32_16x16x32_bf16(a1[m], b1[n], acc[m][n], 0, 0, 0);

    __syncthreads();     // reads consumed (and X(t+1) vm drained) before overwrite
  }

  // epilogue: bf16 C^T write
#pragma unroll
  for (int m = 0; m < 4; ++m) {
    const int r = rowBase + wr * 64 + m * 16 + (lane >> 4) * 4;
#pragma unroll
    for (int n = 0; n < 4; ++n) {
      const int cc = colBase + wc * 64 + n * 16 + fr;
      ushort4 v;
      v.x = f2bf(acc[m][n][0]);
      v.y = f2bf(acc[m][n][1]);
      v.z = f2bf(acc[m][n][2]);
      v.w = f2bf(acc[m][n][3]);
      *reinterpret_cast<ushort4*>(&Ct[(size_t)cc * M + r]) = v;
    }
  }
#undef LOADX
#undef WRITE_A
#undef STAGE_B1
}

// ---- GEMM2b: 128x256 tile, BK=64, single-buffer, 2 blocks/CU (r10, proven) -
__launch_bounds__(512, 4)
__global__ void gemm2b_k(const u16* __restrict__ A, int lda,
                         const u16* __restrict__ Bt, int ldb,
                         float* __restrict__ C, int ldc,
                         const float* __restrict__ bias, int K,
                         int nMT, int nNT, size_t zBt, size_t zC) {
  __shared__ __align__(16) u16 lds[24576];  // 48 KiB

  const int tid = threadIdx.x;
  const int lane = tid & 63;
  const int wid = tid >> 6;
  const int wr = wid >> 2;
  const int wc = wid & 3;

  const int flat = blockIdx.x;
  const int cpx = (int)gridDim.x >> 3;
  const int wg = (flat & 7) * cpx + (flat >> 3);
  const int m_t = wg % nMT;
  const int rest = wg / nMT;
  const int n_t = rest % nNT;
  const int b = rest / nNT;
  const int rowBase = m_t * 128;
  const int colBase = n_t * 256;
  const u16* Bb = Bt + (size_t)b * zBt;

  const int lr = tid >> 3;
  const int kkl = (tid & 7) * 8;
  const int kswz = kkl ^ ((lr & 7) << 3);
  const u16* gA = A + (size_t)(rowBase + lr) * lda + kswz;
  const u16* gB = Bb + (size_t)(colBase + lr) * ldb + kswz;
  u16* lA = lds + lr * 64 + kkl;
  u16* lB = lds + 8192 + lr * 64 + kkl;

  const int fr = lane & 15;
  const int rswz = (lane & 7) << 3;
  const int kp0 = ((lane >> 4) * 8) ^ rswz;
  const int kp1 = (32 | ((lane >> 4) * 8)) ^ rswz;
  const u16* fA = lds + (wr * 64 + fr) * 64;
  const u16* fB = lds + 8192 + (wc * 64 + fr) * 64;

  f32x4 acc[4][4] = {};
  const int NT = K >> 6;

  for (int t = 0; t < NT; ++t) {
    gload16(gA + (size_t)t * 64, lA);
    gload16(gA + (size_t)64 * lda + (size_t)t * 64, lA + 4096);
#pragma unroll
    for (int r4 = 0; r4 < 4; ++r4)
      gload16(gB + (size_t)(r4 * 64) * ldb + (size_t)t * 64, lB + r4 * 4096);
    __syncthreads();

    bf16x8 a[4], bb[4];
#pragma unroll
    for (int m = 0; m < 4; ++m) a[m] = *(const bf16x8*)(fA + m * 1024 + kp0);
#pragma unroll
    for (int n = 0; n < 4; ++n) bb[n] = *(const bf16x8*)(fB + n * 1024 + kp0);
#pragma unroll
    for (int m = 0; m < 4; ++m)
#pragma unroll
      for (int n = 0; n < 4; ++n)
        acc[m][n] = __builtin_amdgcn_mfma_f32_16x16x32_bf16(a[m], bb[n], acc[m][n], 0, 0, 0);
#pragma unroll
    for (int m = 0; m < 4; ++m) a[m] = *(const bf16x8*)(fA + m * 1024 + kp1);
#pragma unroll
    for (int n = 0; n < 4; ++n) bb[n] = *(const bf16x8*)(fB + n * 1024 + kp1);
#pragma unroll
    for (int m = 0; m < 4; ++m)
#pragma unroll
      for (int n = 0; n < 4; ++n)
        acc[m][n] = __builtin_amdgcn_mfma_f32_16x16x32_bf16(a[m], bb[n], acc[m][n], 0, 0, 0);

    __syncthreads();
  }

  float* Cb = C + (size_t)b * zC;
#pragma unroll
  for (int n = 0; n < 4; ++n) {
    const int cc = colBase + wc * 64 + n * 16 + fr;
    const float bv = bias[cc];
#pragma unroll
    for (int m = 0; m < 4; ++m) {
      const int r = rowBase + wr * 64 + m * 16 + (lane >> 4) * 4;
#pragma unroll
      for (int j = 0; j < 4; ++j)
        Cb[(size_t)(r + j) * ldc + cc] = acc[m][n][j] + bv;
    }
  }
}

extern "C" void kernel_launch(void* const* d_in, const int* in_sizes, int n_in,
                              void* d_out, int out_size, void* d_ws, size_t ws_size,
                              hipStream_t stream) {
  const int B = 16, N = 2048, FIN = 512, FOUT = 512;
  const float* x    = (const float*)d_in[0];
  const float* adj  = (const float*)d_in[1];
  const float* w    = (const float*)d_in[2];
  const float* bias = (const float*)d_in[3];
  float* out = (float*)d_out;
  char* ws = (char*)d_ws;

  float* dis = (float*)ws;                       // 8 KB
  u16* wt    = (u16*)(ws + 8192);                // 512 KB  W^T [FOUT][FIN]
  u16* nadj  = (u16*)(ws + 532480);              // 8 MB    [N][N]
  u16* st    = (u16*)(ws + 8921088);             // 32 MB   support^T [FOUT][B*N]

  row_deg_k<<<N, 256, 0, stream>>>(adj, dis, N);
  conv_wt_k<<<(FIN * FOUT) / 256, 256, 0, stream>>>(w, wt);
  make_nadj_k<<<(N * N / 4) / 256, 256, 0, stream>>>(adj, dis, nadj, N);

  // GEMM1e: st = (x @ wt^T)^T ; grid 256m*2n = 512 blocks (2/CU)
  gemm1e_k<<<dim3(512), 512, 0, stream>>>(x, wt, st, B * N);

  // GEMM2b: out[b] = nadj @ support[b] + bias ; grid 16*2*16 = 512 (2/CU)
  gemm2b_k<<<dim3(512), 512, 0, stream>>>(
      nadj, N, st, B * N, out, FOUT, bias, N, 16, 2,
      (size_t)N, (size_t)N * FOUT);
}

// Round 15
// 110.695 us; speedup vs baseline: 1.1251x; 1.0361x over previous
//
#include <hip/hip_runtime.h>
#include <hip/hip_bf16.h>
#include <stdint.h>

typedef __attribute__((ext_vector_type(8))) __bf16 bf16x8;
typedef __attribute__((ext_vector_type(4))) float f32x4;
typedef unsigned short u16;

__device__ __forceinline__ u16 f2bf(float f) {
  unsigned u = __builtin_bit_cast(unsigned, f);
  unsigned r = 0x7FFFu + ((u >> 16) & 1u);
  return (u16)((u + r) >> 16);
}

__device__ __forceinline__ u16 f2bf_hw(float f) {
  __hip_bfloat16 h = __float2bfloat16(f);
  return __builtin_bit_cast(u16, h);
}

__device__ __forceinline__ void gload16(const void* g, void* l) {
  __builtin_amdgcn_global_load_lds(
      (__attribute__((address_space(1))) void*)(g),
      (__attribute__((address_space(3))) void*)(l),
      16, 0, 0);
}

// ---- fused prep: row-deg rsqrt (blocks 0..2047) + W^T cast (2048..3071) ----
__global__ void prep_k(const float* __restrict__ adj, float* __restrict__ dis,
                       const float* __restrict__ w, u16* __restrict__ wt, int N) {
  if ((int)blockIdx.x < N) {
    int row = blockIdx.x;
    const float4* a = (const float4*)(adj + (size_t)row * N);
    float s = 0.f;
    for (int j = threadIdx.x; j < N / 4; j += 256) {
      float4 v = a[j];
      s += v.x + v.y + v.z + v.w;
    }
#pragma unroll
    for (int off = 32; off > 0; off >>= 1) s += __shfl_down(s, off, 64);
    __shared__ float wsum[4];
    if ((threadIdx.x & 63) == 0) wsum[threadIdx.x >> 6] = s;
    __syncthreads();
    if (threadIdx.x == 0) {
      float t = wsum[0] + wsum[1] + wsum[2] + wsum[3];
      dis[row] = (t > 0.f) ? (1.0f / sqrtf(t)) : 0.f;
    }
  } else {
    int idx = ((int)blockIdx.x - N) * 256 + threadIdx.x;  // 262144 total
    int i = idx >> 9, o = idx & 511;
    wt[o * 512 + i] = f2bf(w[idx]);
  }
}

// ---- norm_adj bf16 ---------------------------------------------------------
__global__ void make_nadj_k(const float* __restrict__ adj, const float* __restrict__ dis,
                            u16* __restrict__ o, int N) {
  int idx = blockIdx.x * 256 + threadIdx.x;  // per float4, N*N/4 total
  int i = idx >> 9;                          // N/4 = 512 float4 per row
  int j4 = (idx & 511) * 4;
  float di = dis[i];
  float4 a = ((const float4*)adj)[idx];
  ushort4 u;
  u.x = f2bf(a.x * di * dis[j4 + 0]);
  u.y = f2bf(a.y * di * dis[j4 + 1]);
  u.z = f2bf(a.z * di * dis[j4 + 2]);
  u.w = f2bf(a.w * di * dis[j4 + 3]);
  ((ushort4*)o)[idx] = u;
}

// ---- GEMM1 (fused x-cast): Ct = (X @ Wt^T)^T -------------------------------
// 256x256 tile, BK=64, 8 waves, 1 block/CU. A = fp32 X reg-staged + cvt +
// swizzled ds_write (issue-early/write-late); B = gload_lds w/ pre-swz source.
// Block mapping pairs the two n-tiles of each m-tile on adjacent wg (same
// XCD chunk) so the shared X-slab L2-hits for the sibling (r11-proven).
__launch_bounds__(512, 2)
__global__ void gemm1_xw_k(const float* __restrict__ X,
                           const u16* __restrict__ Wt,
                           u16* __restrict__ Ct, int M) {
  __shared__ __align__(16) u16 lds[65536];

  const int tid = threadIdx.x;
  const int lane = tid & 63;
  const int wid = tid >> 6;
  const int wr = wid >> 2;
  const int wc = wid & 3;

  const int flat = blockIdx.x;
  const int wg = (flat & 7) * 32 + (flat >> 3);
  const int m_t = wg >> 1;   // n-pair of one m-tile are wg,wg+1: same XCD chunk
  const int n_t = wg & 1;
  const int rowBase = m_t * 256;
  const int colBase = n_t * 256;

  const int lr = tid >> 3;
  const int kkl = (tid & 7) * 8;
  const int s = (lr & 7) << 3;
  const int kswz = kkl ^ s;
  const float* gX = X + (size_t)(rowBase + lr) * 512 + kkl;
  const u16* gB = Wt + (size_t)(colBase + lr) * 512 + kswz;
  u16* lAsw = lds + lr * 64 + kswz;
  u16* lB = lds + 32768 + lr * 64 + kkl;

  const int fr = lane & 15;
  const int rswz = (lane & 7) << 3;
  const int kp0 = ((lane >> 4) * 8) ^ rswz;
  const int kp1 = (32 | ((lane >> 4) * 8)) ^ rswz;
  const u16* fA = lds + (wr * 128 + fr) * 64;
  const u16* fB = lds + 32768 + (wc * 64 + fr) * 64;

  f32x4 acc[8][4] = {};
  f32x4 xv[4][2];

  const int NT = 8;  // K = 512

#define LOADX(t)                                                                     \
  _Pragma("unroll") for (int r4 = 0; r4 < 4; ++r4) {                                 \
    xv[r4][0] = *(const f32x4*)(gX + (size_t)(r4 * 64) * 512 + (t) * 64);            \
    xv[r4][1] = *(const f32x4*)(gX + (size_t)(r4 * 64) * 512 + (t) * 64 + 4);        \
  }

#define STAGE_B1(d, t)                                                               \
  _Pragma("unroll") for (int r4 = 0; r4 < 4; ++r4)                                   \
    gload16(gB + (size_t)(r4 * 64) * 512 + (size_t)(t) * 64,                         \
            lB + (d) * 16384 + r4 * 4096);

#define WRITE_A(d)                                                                   \
  _Pragma("unroll") for (int r4 = 0; r4 < 4; ++r4) {                                 \
    bf16x8 v;                                                                        \
    _Pragma("unroll") for (int i = 0; i < 4; ++i) {                                  \
      v[i] = __builtin_bit_cast(__bf16, f2bf_hw(xv[r4][0][i]));                      \
      v[4 + i] = __builtin_bit_cast(__bf16, f2bf_hw(xv[r4][1][i]));                  \
    }                                                                                \
    *(bf16x8*)(lAsw + (d) * 16384 + r4 * 4096) = v;                                  \
  }

  LOADX(0);
  STAGE_B1(0, 0);
  WRITE_A(0);
  __syncthreads();

  for (int t = 0; t < NT; ++t) {
    const int c = t & 1;
    const int cn = c ^ 1;
    const int tn = (t + 1 < NT) ? t + 1 : NT - 1;

    LOADX(tn);
    STAGE_B1(cn, tn);
    __builtin_amdgcn_sched_barrier(0);

    bf16x8 a0[8], a1[8], b0[4], b1[4];
#pragma unroll
    for (int m = 0; m < 8; ++m) {
      a0[m] = *(const bf16x8*)(fA + c * 16384 + m * 1024 + kp0);
      a1[m] = *(const bf16x8*)(fA + c * 16384 + m * 1024 + kp1);
    }
#pragma unroll
    for (int n = 0; n < 4; ++n) {
      b0[n] = *(const bf16x8*)(fB + c * 16384 + n * 1024 + kp0);
      b1[n] = *(const bf16x8*)(fB + c * 16384 + n * 1024 + kp1);
    }
#pragma unroll
    for (int m = 0; m < 8; ++m)
#pragma unroll
      for (int n = 0; n < 4; ++n)
        acc[m][n] = __builtin_amdgcn_mfma_f32_16x16x32_bf16(a0[m], b0[n], acc[m][n], 0, 0, 0);
#pragma unroll
    for (int m = 0; m < 8; ++m)
#pragma unroll
      for (int n = 0; n < 4; ++n)
        acc[m][n] = __builtin_amdgcn_mfma_f32_16x16x32_bf16(a1[m], b1[n], acc[m][n], 0, 0, 0);

    __builtin_amdgcn_sched_barrier(0);
    WRITE_A(cn);
    __syncthreads();
  }

#pragma unroll
  for (int m = 0; m < 8; ++m) {
    const int r = rowBase + wr * 128 + m * 16 + (lane >> 4) * 4;
#pragma unroll
    for (int n = 0; n < 4; ++n) {
      const int cc = colBase + wc * 64 + n * 16 + (lane & 15);
      ushort4 v;
      v.x = f2bf(acc[m][n][0]);
      v.y = f2bf(acc[m][n][1]);
      v.z = f2bf(acc[m][n][2]);
      v.w = f2bf(acc[m][n][3]);
      *reinterpret_cast<ushort4*>(&Ct[(size_t)cc * M + r]) = v;
    }
  }
#undef LOADX
#undef STAGE_B1
#undef WRITE_A
}

// ---- GEMM2b: 128x256 tile, BK=64, single-buffer, 2 blocks/CU (r10, proven) -
__launch_bounds__(512, 4)
__global__ void gemm2b_k(const u16* __restrict__ A, int lda,
                         const u16* __restrict__ Bt, int ldb,
                         float* __restrict__ C, int ldc,
                         const float* __restrict__ bias, int K,
                         int nMT, int nNT, size_t zBt, size_t zC) {
  __shared__ __align__(16) u16 lds[24576];  // 48 KiB

  const int tid = threadIdx.x;
  const int lane = tid & 63;
  const int wid = tid >> 6;
  const int wr = wid >> 2;
  const int wc = wid & 3;

  const int flat = blockIdx.x;
  const int cpx = (int)gridDim.x >> 3;
  const int wg = (flat & 7) * cpx + (flat >> 3);
  const int m_t = wg % nMT;
  const int rest = wg / nMT;
  const int n_t = rest % nNT;
  const int b = rest / nNT;
  const int rowBase = m_t * 128;
  const int colBase = n_t * 256;
  const u16* Bb = Bt + (size_t)b * zBt;

  const int lr = tid >> 3;
  const int kkl = (tid & 7) * 8;
  const int kswz = kkl ^ ((lr & 7) << 3);
  const u16* gA = A + (size_t)(rowBase + lr) * lda + kswz;
  const u16* gB = Bb + (size_t)(colBase + lr) * ldb + kswz;
  u16* lA = lds + lr * 64 + kkl;
  u16* lB = lds + 8192 + lr * 64 + kkl;

  const int fr = lane & 15;
  const int rswz = (lane & 7) << 3;
  const int kp0 = ((lane >> 4) * 8) ^ rswz;
  const int kp1 = (32 | ((lane >> 4) * 8)) ^ rswz;
  const u16* fA = lds + (wr * 64 + fr) * 64;
  const u16* fB = lds + 8192 + (wc * 64 + fr) * 64;

  f32x4 acc[4][4] = {};
  const int NT = K >> 6;

  for (int t = 0; t < NT; ++t) {
    gload16(gA + (size_t)t * 64, lA);
    gload16(gA + (size_t)64 * lda + (size_t)t * 64, lA + 4096);
#pragma unroll
    for (int r4 = 0; r4 < 4; ++r4)
      gload16(gB + (size_t)(r4 * 64) * ldb + (size_t)t * 64, lB + r4 * 4096);
    __syncthreads();

    bf16x8 a[4], bb[4];
#pragma unroll
    for (int m = 0; m < 4; ++m) a[m] = *(const bf16x8*)(fA + m * 1024 + kp0);
#pragma unroll
    for (int n = 0; n < 4; ++n) bb[n] = *(const bf16x8*)(fB + n * 1024 + kp0);
#pragma unroll
    for (int m = 0; m < 4; ++m)
#pragma unroll
      for (int n = 0; n < 4; ++n)
        acc[m][n] = __builtin_amdgcn_mfma_f32_16x16x32_bf16(a[m], bb[n], acc[m][n], 0, 0, 0);
#pragma unroll
    for (int m = 0; m < 4; ++m) a[m] = *(const bf16x8*)(fA + m * 1024 + kp1);
#pragma unroll
    for (int n = 0; n < 4; ++n) bb[n] = *(const bf16x8*)(fB + n * 1024 + kp1);
#pragma unroll
    for (int m = 0; m < 4; ++m)
#pragma unroll
      for (int n = 0; n < 4; ++n)
        acc[m][n] = __builtin_amdgcn_mfma_f32_16x16x32_bf16(a[m], bb[n], acc[m][n], 0, 0, 0);

    __syncthreads();
  }

  float* Cb = C + (size_t)b * zC;
#pragma unroll
  for (int n = 0; n < 4; ++n) {
    const int cc = colBase + wc * 64 + n * 16 + fr;
    const float bv = bias[cc];
#pragma unroll
    for (int m = 0; m < 4; ++m) {
      const int r = rowBase + wr * 64 + m * 16 + (lane >> 4) * 4;
#pragma unroll
      for (int j = 0; j < 4; ++j)
        Cb[(size_t)(r + j) * ldc + cc] = acc[m][n][j] + bv;
    }
  }
}

extern "C" void kernel_launch(void* const* d_in, const int* in_sizes, int n_in,
                              void* d_out, int out_size, void* d_ws, size_t ws_size,
                              hipStream_t stream) {
  const int B = 16, N = 2048, FIN = 512, FOUT = 512;
  const float* x    = (const float*)d_in[0];
  const float* adj  = (const float*)d_in[1];
  const float* w    = (const float*)d_in[2];
  const float* bias = (const float*)d_in[3];
  float* out = (float*)d_out;
  char* ws = (char*)d_ws;

  float* dis = (float*)ws;                       // 8 KB
  u16* wt    = (u16*)(ws + 8192);                // 512 KB  W^T [FOUT][FIN]
  u16* nadj  = (u16*)(ws + 532480);              // 8 MB    [N][N]
  u16* st    = (u16*)(ws + 8921088);             // 32 MB   support^T [FOUT][B*N]

  // fused prep: row-deg (2048 blocks) + W^T cast (1024 blocks)
  prep_k<<<N + (FIN * FOUT) / 256, 256, 0, stream>>>(adj, dis, w, wt, N);
  make_nadj_k<<<(N * N / 4) / 256, 256, 0, stream>>>(adj, dis, nadj, N);

  // GEMM1 (fused x->bf16): st = (x @ wt^T)^T ; grid 128*2 = 256 blocks
  gemm1_xw_k<<<dim3(256), 512, 0, stream>>>(x, wt, st, B * N);

  // GEMM2: out[b] = nadj @ support[b] + bias ; grid 16*2*16 = 512 blocks (2/CU)
  gemm2b_k<<<dim3(512), 512, 0, stream>>>(
      nadj, N, st, B * N, out, FOUT, bias, N, 16, 2,
      (size_t)N, (size_t)N * FOUT);
}